// Round 8
// baseline (3756.791 us; speedup 1.0000x reference)
//
#include <hip/hip_runtime.h>

#define NT 512
#define TRAJ 4

constexpr int Lk = 200;
constexpr int NSTEPS = 100;

typedef float f32x2 __attribute__((ext_vector_type(2)));
typedef float f32x4 __attribute__((ext_vector_type(4)));
typedef short s16x8 __attribute__((ext_vector_type(8)));

#if __has_builtin(__builtin_elementwise_fma)
#define FMA2(a, b, c) __builtin_elementwise_fma((a), (b), (c))
#else
static __device__ __forceinline__ f32x2 fma2_(f32x2 a, f32x2 b, f32x2 c) {
    c.x = fmaf(a.x, b.x, c.x); c.y = fmaf(a.y, b.y, c.y); return c;
}
#define FMA2 fma2_
#endif

// Stable softplus, matches jax.nn.softplus in fp32: max(x,0) + log1p(exp(-|x|))
__device__ __forceinline__ float sp_act(float x) {
    return fmaxf(x, 0.0f) + log1pf(expf(-fabsf(x)));
}

// fp32 -> bf16 round-to-nearest-even
__device__ __forceinline__ unsigned short f2bf(float f) {
    union { float f; unsigned int u; } v; v.f = f;
    unsigned int u = v.u + 0x7FFFu + ((v.u >> 16) & 1u);
    return (unsigned short)(u >> 16);
}

// Pack fW3 [2048][128] fp32 -> bf16 B-fragments for mfma_f32_16x16x32_bf16.
// Slot s = (tile*4 + ks)*64 + lane holds 8 bf16: B[k = ks*32 + (lane>>4)*8 + j][n = tile*16 + (lane&15)]
// (byte-identical to the round-4/5 pack that verified correct)
__global__ void fw3_packb(const float* __restrict__ w, unsigned short* __restrict__ p) {
    const int s = blockIdx.x * 256 + threadIdx.x;   // 0..32767
    const int tg = s >> 8;
    const int ks = (s >> 6) & 3;
    const int l  = s & 63;
    const int n  = tg * 16 + (l & 15);
    const int k0 = ks * 32 + (l >> 4) * 8;
    unsigned short out[8];
    #pragma unroll
    for (int j = 0; j < 8; ++j) out[j] = f2bf(w[n * 128 + k0 + j]);
    *(uint4*)(p + (size_t)s * 8) = *(const uint4*)out;
}

// Stage global weight W[O][I] (row-major) into LDS transposed T[I][O].
template<int O, int I>
__device__ __forceinline__ void stage_T(const float* __restrict__ g, float* __restrict__ T) {
    for (int base = threadIdx.x * 4; base < O * I; base += NT * 4) {
        const float4 w = *(const float4*)(g + base);
        const int o = base / I;
        const int i = base % I;
        T[(i + 0) * O + o] = w.x;
        T[(i + 1) * O + o] = w.y;
        T[(i + 2) * O + o] = w.z;
        T[(i + 3) * O + o] = w.w;
    }
}

// out[t][o] = act(bias[o] + sum_i in[t][i] * T[i][o]); ACT: 0=none,1=softplus,2=relu
template<int I, int O, int ACT>
__device__ __forceinline__ void mlp_layer(const float* __restrict__ T,
                                          const float* __restrict__ bias,
                                          const float* __restrict__ in, int inStride,
                                          float* __restrict__ out, int outStride) {
    const int tid = threadIdx.x;
    constexpr int TOT = TRAJ * O;
    for (int e = tid; e < TOT; e += NT) {
        const int t = e / O;
        const int o = e % O;
        const float* inr = in + t * inStride;
        f32x2 a2; a2.x = bias[o]; a2.y = 0.0f;
        #pragma unroll 4
        for (int i = 0; i < I; i += 2) {
            f32x2 xv; xv.x = inr[i];        xv.y = inr[i + 1];
            f32x2 wv; wv.x = T[i * O + o];  wv.y = T[(i + 1) * O + o];
            a2 = FMA2(xv, wv, a2);
        }
        float acc = a2.x + a2.y;
        if (ACT == 1) acc = sp_act(acc);
        else if (ACT == 2) acc = fmaxf(acc, 0.0f);
        out[t * outStride + o] = acc;
    }
}

// Issue B-fragments of tile (S*8 + wave) into a named register buffer (literal indices only).
#define ISSUE_S(S, BUF) do {                                      \
    BUF[0] = wq[(((S) * 8 + wave) * 4 + 0) * 64];                 \
    BUF[1] = wq[(((S) * 8 + wave) * 4 + 1) * 64];                 \
    BUF[2] = wq[(((S) * 8 + wave) * 4 + 2) * 64];                 \
    BUF[3] = wq[(((S) * 8 + wave) * 4 + 3) * 64];                 \
} while (0)

// One step: tile = S*8 + wave. 4 MFMAs, fused bias + dX (this wave's d-half),
// 16-lane d-half reduce, lane-0 writes the half-dot to khalf[wave][S][0..3].
#define STEPM(S, BUF) do {                                                                  \
    f32x4 acc_ = {0.f, 0.f, 0.f, 0.f};                                                      \
    acc_ = __builtin_amdgcn_mfma_f32_16x16x32_bf16(afrag[0], *(const s16x8*)&BUF[0], acc_, 0, 0, 0); \
    acc_ = __builtin_amdgcn_mfma_f32_16x16x32_bf16(afrag[1], *(const s16x8*)&BUF[1], acc_, 0, 0, 0); \
    acc_ = __builtin_amdgcn_mfma_f32_16x16x32_bf16(afrag[2], *(const s16x8*)&BUF[2], acc_, 0, 0, 0); \
    acc_ = __builtin_amdgcn_mfma_f32_16x16x32_bf16(afrag[3], *(const s16x8*)&BUF[3], acc_, 0, 0, 0); \
    const float bb_ = fb3s[((S) * 8 + wave) * 16 + (lane & 15)];                            \
    float p0_ = (acc_[0] + bb_) * dxr0;                                                     \
    float p1_ = (acc_[1] + bb_) * dxr1;                                                     \
    float p2_ = (acc_[2] + bb_) * dxr2;                                                     \
    float p3_ = (acc_[3] + bb_) * dxr3;                                                     \
    _Pragma("unroll")                                                                       \
    for (int m_ = 1; m_ < 16; m_ <<= 1) {                                                   \
        p0_ += __shfl_xor(p0_, m_, 64); p1_ += __shfl_xor(p1_, m_, 64);                     \
        p2_ += __shfl_xor(p2_, m_, 64); p3_ += __shfl_xor(p3_, m_, 64);                     \
    }                                                                                       \
    if (lane == 0) {                                                                        \
        f32x4 pv_; pv_[0] = p0_; pv_[1] = p1_; pv_[2] = p2_; pv_[3] = p3_;                  \
        *(f32x4*)(khalf + (wave * 16 + (S)) * 4) = pv_;                                     \
    }                                                                                       \
} while (0)

__global__ __launch_bounds__(NT, 1)
void cde_kernel(const float* __restrict__ ts,
                const float* __restrict__ coef_d, const float* __restrict__ coef_c,
                const float* __restrict__ coef_b, const float* __restrict__ coef_a,
                const float* __restrict__ iW1, const float* __restrict__ ib1,
                const float* __restrict__ iW2, const float* __restrict__ ib2,
                const float* __restrict__ iW3, const float* __restrict__ ib3,
                const float* __restrict__ fW1, const float* __restrict__ fb1,
                const float* __restrict__ fW2, const float* __restrict__ fb2,
                const float* __restrict__ fb3,
                const float* __restrict__ dW1, const float* __restrict__ db1,
                const float* __restrict__ dW2, const float* __restrict__ db2,
                const float* __restrict__ dW3, const float* __restrict__ db3,
                const unsigned short* __restrict__ fW3B,
                float* __restrict__ outp)
{
    // wreg phase-union (proven 123904-B layout from rounds 4/5):
    //  init: iT1+iT2+iT3 = 28672 f. main: wT1(8192)+wT2(16384)=24576, fb3s @24576 (2048),
    //  h2f bf16 @26624 (1024 f). decoder: dT1+dT2+dT3 = 26624 (overlaps dead fb3s).
    __shared__ __align__(16) float wreg[28672];
    __shared__ __align__(16) float h1s[TRAJ * 128];   // layer1 out; overlaid as khalf in MFMA phase
    __shared__ float h2s[TRAJ * 128];
    __shared__ float ys[TRAJ * 64], ys2[TRAJ * 64], k1s[TRAJ * 64];
    __shared__ float dXs[TRAJ * 32], a0s[TRAJ * 32];
    __shared__ float fb1s[128], fb2s[128];

    float* const fb3s = wreg + 24576;                              // [2048]
    unsigned short* const h2f = (unsigned short*)(wreg + 26624);   // [2048] bf16, fragment order
    float* const khalf = h1s;                                      // [8 waves][16 steps][4 traj]

    const int tid  = threadIdx.x;
    const int lane = tid & 63;
    const int wave = tid >> 6;
    const int bbase = blockIdx.x * TRAJ;

    const float ts0 = ts[0];
    const float dt = (ts[Lk - 1] - ts0) / (float)NSTEPS;
    const float hdt = 0.5f * dt;
    const uint4* wq = (const uint4*)fW3B + lane;

    // ---- initial condition: y0 = sp(MLP_i(coef_a[:,0,:])) ----
    if (tid < TRAJ * 32) {
        const int t = tid >> 5, d = tid & 31;
        a0s[t * 32 + d] = coef_a[((size_t)(bbase + t) * 199) * 32 + d];
    }
    stage_T<128, 32>(iW1, wreg);                       // iT1 [32][128]
    stage_T<128, 128>(iW2, wreg + 32 * 128);           // iT2 [128][128]
    stage_T<64, 128>(iW3, wreg + 32 * 128 + 128 * 128);// iT3 [128][64]
    if (tid < 128) { fb1s[tid] = fb1[tid]; fb2s[tid] = fb2[tid]; }
    __syncthreads();
    mlp_layer<32, 128, 1>(wreg, ib1, a0s, 32, h1s, 128);
    __syncthreads();
    mlp_layer<128, 128, 1>(wreg + 32 * 128, ib2, h1s, 128, h2s, 128);
    __syncthreads();
    mlp_layer<128, 64, 1>(wreg + 32 * 128 + 128 * 128, ib3, h2s, 128, ys, 64);
    __syncthreads();

    // ---- stage vf weights + fb3 + zero h2f pad rows (resident for all 200 evals) ----
    stage_T<128, 64>(fW1, wreg);                       // wT1 [64][128]
    stage_T<128, 128>(fW2, wreg + 64 * 128);           // wT2 [128][128]
    for (int i = tid * 4; i < 2048; i += NT * 4)
        *(float4*)(fb3s + i) = *(const float4*)(fb3 + i);
    for (int i = tid; i < 2048; i += NT) h2f[i] = 0;   // A rows t=4..15 stay zero
    __syncthreads();

    // ---- Heun, 100 steps = 200 evals ----
    #pragma unroll 1
    for (int e = 0; e < 2 * NSTEPS; ++e) {
        const bool k2e = e & 1;
        const float t1 = ts0 + (float)(e >> 1) * dt + (k2e ? dt : 0.0f);
        const float* yin  = k2e ? ys2 : ys;
        float*       yout = k2e ? ys  : ys2;

        // cubic-spline derivative dX/dt at scalar time t1
        if (tid < TRAJ * 32) {
            int i = (int)floorf(t1);
            i = min(max(i, 0), Lk - 2);
            const float frac = t1 - ts[i];
            const int tt = tid >> 5, d = tid & 31;
            const size_t off = ((size_t)(bbase + tt) * 199 + (size_t)i) * 32 + d;
            dXs[tid] = coef_b[off] + frac * (2.0f * coef_c[off] + 3.0f * frac * coef_d[off]);
        }

        // Prefetch ring: 3 named slots, issued 3 steps ahead. First 3 issues hide
        // under the two small MLP layers. All indices literal (R2 scratch lesson).
        uint4 sA[4], sB[4], sC[4];
        ISSUE_S(0, sA); ISSUE_S(1, sB); ISSUE_S(2, sC);

        mlp_layer<64, 128, 1>(wreg, fb1s, yin, 64, h1s, 128);
        __syncthreads();

        // layer2 -> bf16, written directly in MFMA A-fragment order:
        // h2f[((o>>3)*16 + t)*8 + (o&7)]   (proven conflict-free in round 5)
        {
            const int t = tid >> 7, o = tid & 127;
            const float* inr = h1s + t * 128;
            f32x2 a2; a2.x = fb2s[o]; a2.y = 0.0f;
            #pragma unroll 4
            for (int i = 0; i < 128; i += 2) {
                f32x2 xv; xv.x = inr[i];                   xv.y = inr[i + 1];
                f32x2 wv; wv.x = wreg[64*128 + i*128 + o]; wv.y = wreg[64*128 + (i+1)*128 + o];
                a2 = FMA2(xv, wv, a2);
            }
            h2f[((o >> 3) * 16 + t) * 8 + (o & 7)] = f2bf(sp_act(a2.x + a2.y));
        }
        __syncthreads();

        // A-fragments (conflict-free: byte addr = lane*16 + ks*1024)
        s16x8 afrag[4];
        #pragma unroll
        for (int ks = 0; ks < 4; ++ks)
            afrag[ks] = *(const s16x8*)(h2f + ((ks * 4 + (lane >> 4)) * 16 + (lane & 15)) * 8);

        // This wave's d-half: tile parity = wave&1 -> d = (wave&1)*16 + (lane&15)
        const int dbase = (wave & 1) * 16 + (lane & 15);
        const float dxr0 = dXs[0 * 32 + dbase];
        const float dxr1 = dXs[1 * 32 + dbase];
        const float dxr2 = dXs[2 * 32 + dbase];
        const float dxr3 = dXs[3 * 32 + dbase];

        // 16 steps; at step s the BLOCK collectively reads one contiguous 32 KB
        // window (tiles s*8 .. s*8+7), sweeping the 512 KB buffer sequentially —
        // the L2-friendly order (R0/R7 proven); never 8 disjoint streams (R4 bug).
        STEPM(0,  sA); ISSUE_S(3,  sA);
        STEPM(1,  sB); ISSUE_S(4,  sB);
        STEPM(2,  sC); ISSUE_S(5,  sC);
        STEPM(3,  sA); ISSUE_S(6,  sA);
        STEPM(4,  sB); ISSUE_S(7,  sB);
        STEPM(5,  sC); ISSUE_S(8,  sC);
        STEPM(6,  sA); ISSUE_S(9,  sA);
        STEPM(7,  sB); ISSUE_S(10, sB);
        STEPM(8,  sC); ISSUE_S(11, sC);
        STEPM(9,  sA); ISSUE_S(12, sA);
        STEPM(10, sB); ISSUE_S(13, sB);
        STEPM(11, sC); ISSUE_S(14, sC);
        STEPM(12, sA); ISSUE_S(15, sA);
        STEPM(13, sB);
        STEPM(14, sC);
        STEPM(15, sA);
        __syncthreads();

        // Combine d-halves across wave pairs + fused Heun update.
        // h = step*4 + w2 (w2 = wave>>1); halves in waves 2*w2 (d 0-15) and 2*w2+1 (d 16-31).
        if (tid < 256) {
            const int r = tid & 3, step = (tid >> 2) & 15, w2 = tid >> 6;
            const float kq = khalf[((2 * w2) * 16 + step) * 4 + r]
                           + khalf[((2 * w2 + 1) * 16 + step) * 4 + r];
            const int idx = r * 64 + step * 4 + w2;
            if (!k2e) { k1s[idx] = kq; yout[idx] = ys[idx] + dt * kq; }
            else      {                yout[idx] = ys[idx] + hdt * (k1s[idx] + kq); }
        }
        __syncthreads();
    }

    // ---- decoder: Linear->relu->Linear->relu->Linear ----
    stage_T<128, 64>(dW1, wreg);                          // dT1 [64][128]
    stage_T<128, 128>(dW2, wreg + 64 * 128);              // dT2 [128][128]
    stage_T<16, 128>(dW3, wreg + 64 * 128 + 128 * 128);   // dT3 [128][16] (overlaps dead fb3s)
    __syncthreads();
    mlp_layer<64, 128, 2>(wreg, db1, ys, 64, h1s, 128);
    __syncthreads();
    mlp_layer<128, 128, 2>(wreg + 64 * 128, db2, h1s, 128, h2s, 128);
    __syncthreads();
    mlp_layer<128, 16, 0>(wreg + 64 * 128 + 128 * 128, db3, h2s, 128,
                          outp + (size_t)bbase * 16, 16);
}

extern "C" void kernel_launch(void* const* d_in, const int* in_sizes, int n_in,
                              void* d_out, int out_size, void* d_ws, size_t ws_size,
                              hipStream_t stream) {
    (void)in_sizes; (void)n_in; (void)out_size; (void)ws_size;
    const float* ts     = (const float*)d_in[0];
    const float* coef_d = (const float*)d_in[1];
    const float* coef_c = (const float*)d_in[2];
    const float* coef_b = (const float*)d_in[3];
    const float* coef_a = (const float*)d_in[4];
    const float* iW1 = (const float*)d_in[5];  const float* ib1 = (const float*)d_in[6];
    const float* iW2 = (const float*)d_in[7];  const float* ib2 = (const float*)d_in[8];
    const float* iW3 = (const float*)d_in[9];  const float* ib3 = (const float*)d_in[10];
    const float* fW1 = (const float*)d_in[11]; const float* fb1 = (const float*)d_in[12];
    const float* fW2 = (const float*)d_in[13]; const float* fb2 = (const float*)d_in[14];
    const float* fW3 = (const float*)d_in[15]; const float* fb3 = (const float*)d_in[16];
    const float* dW1 = (const float*)d_in[17]; const float* db1 = (const float*)d_in[18];
    const float* dW2 = (const float*)d_in[19]; const float* db2 = (const float*)d_in[20];
    const float* dW3 = (const float*)d_in[21]; const float* db3 = (const float*)d_in[22];

    unsigned short* fW3B = (unsigned short*)d_ws;   // 512 KB: fW3 as bf16 B-fragments

    fw3_packb<<<128, 256, 0, stream>>>(fW3, fW3B);
    cde_kernel<<<256, NT, 0, stream>>>(ts, coef_d, coef_c, coef_b, coef_a,
                                       iW1, ib1, iW2, ib2, iW3, ib3,
                                       fW1, fb1, fW2, fb2, fb3,
                                       dW1, db1, dW2, db2, dW3, db3,
                                       fW3B, (float*)d_out);
}